// Round 7
// baseline (157.759 us; speedup 1.0000x reference)
//
#include <hip/hip_runtime.h>

#define NFR 500   // n_frames
#define NFQ 320   // n_freq
#define NB  2     // batch
#define NC  6     // n_chan
#define NS  4     // n_src
#define NBK 2     // n_chan - n_src
#define NT  4     // n_taps
#define NDLY 1    // n_delay
#define EPSF 1e-3f
#define TINYF 1e-20f

#define NP   512            // padded frame count
#define XPAD 8              // leading zero-pad for shifted X reads
#define XLEN (XPAD + NP)
#define NCH  8              // f-chunks for w partial sums
#define FPC  (NFQ / NCH)    // 40 freqs per chunk
#define NI   4              // i-steps per wave (256 frames / 64 lanes)

typedef float f2 __attribute__((ext_vector_type(2)));

__device__ __forceinline__ f2 mk2(float r, float i){ f2 t; t.x = r; t.y = i; return t; }
__device__ __forceinline__ f2 cmul(f2 a, f2 b){ return a.xx*b + a.yy*mk2(-b.y, b.x); }
__device__ __forceinline__ f2 cmulc(f2 a, f2 b){ return b.xx*a + b.yy*mk2(a.y, -a.x); } // a*conj(b)
__device__ __forceinline__ f2 conjc(f2 a){ return mk2(a.x, -a.y); }
__device__ __forceinline__ float cmag2(f2 a){ return a.x*a.x + a.y*a.y; }
__device__ __forceinline__ f2 cinv(f2 a){ float m = a.x*a.x + a.y*a.y; return mk2(a.x/m, -a.y/m); }

// wave64 sum-reduce via DPP (VALU latency); result uniform via readlane(63)
#define DPPF(x, ctrl) __int_as_float(__builtin_amdgcn_mov_dpp(__float_as_int(x), (ctrl), 0xF, 0xF, true))
__device__ __forceinline__ float wred64(float x){
  x += DPPF(x, 0x111);   // row_shr:1
  x += DPPF(x, 0x112);   // row_shr:2
  x += DPPF(x, 0x114);   // row_shr:4
  x += DPPF(x, 0x118);   // row_shr:8
  x += DPPF(x, 0x142);   // row_bcast:15
  x += DPPF(x, 0x143);   // row_bcast:31
  return __int_as_float(__builtin_amdgcn_readlane(__float_as_int(x), 63));
}

// ---------------------------------------------------------------------------
// init: C_XX -> J (4x4 diag-loaded solve), W/A = eye, Y = X[:4], Z = J X - X[4:]
// ---------------------------------------------------------------------------
__global__ __launch_bounds__(256) void k_init(
  const float* __restrict__ Xr, const float* __restrict__ Xi,
  f2* __restrict__ Yg, f2* __restrict__ Zg,
  f2* __restrict__ Wg, f2* __restrict__ Jg, f2* __restrict__ Ag)
{
  __shared__ f2 sX[NC][NFR];
  __shared__ f2 sC[NS][NC];
  __shared__ f2 sJl[NBK][NS];

  const int bf = blockIdx.x;
  const int b = bf / NFQ, f = bf % NFQ;
  const int tid = threadIdx.x, wv = tid >> 6, lane = tid & 63;

  for (int c = 0; c < NC; ++c) {
    const size_t base = ((size_t)(b*NC + c)*NFQ + f)*NFR;
    for (int n = tid; n < NFR; n += 256)
      sX[c][n] = mk2(Xr[base+n], Xi[base+n]);
  }
  __syncthreads();

  for (int p = wv; p < NS*NC; p += 4) {
    int s = p / NC, d = p % NC;
    f2 ar2 = mk2(0.f,0.f), ai2 = mk2(0.f,0.f);
    for (int n = lane; n < NFR; n += 64) {
      f2 xs = sX[s][n], xd = sX[d][n];
      ar2 += xs * xd;
      ai2 += xs.yx * mk2(xd.x, -xd.y);
    }
    float ar = wred64(ar2.x + ar2.y), ai = wred64(ai2.x + ai2.y);
    if (lane == 0) sC[s][d] = mk2(ar*(1.f/NFR), ai*(1.f/NFR));
  }
  __syncthreads();

  if (tid == 0) {
    f2 M[NS][NC];
    for (int s = 0; s < NS; ++s)
      for (int d = 0; d < NC; ++d) M[s][d] = sC[s][d];
    float dsum = 0.f;
    for (int s = 0; s < NS; ++s) dsum += sqrtf(cmag2(M[s][s]));
    float load = fmaxf(dsum*1e-5f, 1e-5f);
    for (int s = 0; s < NS; ++s) M[s][s].x += load;
    for (int col = 0; col < NS; ++col) {
      int piv = col; float best = cmag2(M[col][col]);
      for (int r = col+1; r < NS; ++r) { float m = cmag2(M[r][col]); if (m > best){best=m; piv=r;} }
      if (piv != col) for (int k = 0; k < NC; ++k) { f2 t=M[col][k]; M[col][k]=M[piv][k]; M[piv][k]=t; }
      f2 ip = cinv(M[col][col]);
      for (int k = col; k < NC; ++k) M[col][k] = cmul(M[col][k], ip);
      for (int r = 0; r < NS; ++r) if (r != col) {
        f2 fac = M[r][col];
        for (int k = col; k < NC; ++k) M[r][k] -= cmul(fac, M[col][k]);
      }
    }
    for (int k = 0; k < NBK; ++k)
      for (int s = 0; s < NS; ++s) sJl[k][s] = conjc(M[s][NS+k]);
  }
  __syncthreads();

  if (tid < NBK*NS) {
    int k = tid / NS, s = tid % NS;
    Jg[((size_t)(b*NBK+k)*NFQ + f)*NS + s] = sJl[k][s];
  } else if (tid < NBK*NS + NS*NC) {
    int t = tid - NBK*NS; int s = t / NC, d = t % NC;
    Wg[((size_t)(b*NS+s)*NFQ + f)*NC + d] = (s==d) ? mk2(1.f,0.f) : mk2(0.f,0.f);
  } else if (tid < NBK*NS + NS*NC + NS*NS) {
    int t = tid - NBK*NS - NS*NC; int s = t / NS, d = t % NS;
    Ag[((size_t)(b*NS+s)*NFQ + f)*NS + d] = (s==d) ? mk2(1.f,0.f) : mk2(0.f,0.f);
  }
  for (int c = 0; c < NS; ++c) {
    const size_t base = ((size_t)(b*NS + c)*NFQ + f)*NFR;
    for (int n = tid; n < NFR; n += 256) Yg[base+n] = sX[c][n];
  }
  for (int k = 0; k < NBK; ++k) {
    const size_t base = ((size_t)(b*NBK + k)*NFQ + f)*NFR;
    for (int n = tid; n < NFR; n += 256) {
      f2 acc = -sX[NS+k][n];
      for (int s = 0; s < NS; ++s) acc += cmul(sJl[k][s], sX[s][n]);
      Zg[base+n] = acc;
    }
  }
}

// ---------------------------------------------------------------------------
// w partial sums: wacc[ch][bs][n] = sum_{f in chunk ch} |Y[bs,f,n]|^2
// ---------------------------------------------------------------------------
__global__ __launch_bounds__(512) void k_wpart(const f2* __restrict__ Yg,
                                               float* __restrict__ wacc)
{
  const int bs = blockIdx.x / NCH;
  const int ch = blockIdx.x % NCH;
  const int n  = threadIdx.x;
  if (n >= NFR) return;
  const f2* row = Yg + (size_t)bs*NFQ*NFR;
  f2 acc2 = mk2(0.f,0.f);
  for (int ff = 0; ff < FPC; ++ff) {
    f2 y = row[(size_t)(ch*FPC + ff)*NFR + n];
    acc2 += y*y;
  }
  wacc[((size_t)(ch*NB*NS + bs))*NFR + n] = acc2.x + acc2.y;
}

// ---------------------------------------------------------------------------
// one full iss_updates iteration per (b,f) block. 8 waves = 4 channels x 2
// frame-halves; Y,w in registers; cross-wave reduce via DPP + LDS partials.
// ---------------------------------------------------------------------------
__global__ __launch_bounds__(512, 4) void k_iter(
  const float* __restrict__ Xr, const float* __restrict__ Xi,
  f2* __restrict__ Yg, f2* __restrict__ Zg,
  f2* __restrict__ Wg, f2* __restrict__ Jg, f2* __restrict__ Ag,
  const float* __restrict__ wacc, float* __restrict__ outR, const int last)
{
  __shared__ f2 sXp[NC][XLEN];
  __shared__ f2 sZ[NBK][NP];
  __shared__ f2 sS[NP];
  __shared__ f2 sW[NS][NC];
  __shared__ f2 sJ[NBK][NS];
  __shared__ f2 sA[NS][NS];
  __shared__ f2 sB[NS][2*NS];
  __shared__ f2 sv[NS], sg[NC], sgo[NS];
  __shared__ f2 sAv[NS], sgA[NS], sWsrc[NC];
  __shared__ float sRed[2][8][8];   // [bank][wave][slot]

  const int bf = blockIdx.x;
  const int b = bf / NFQ, f = bf % NFQ;
  const int tid = threadIdx.x, wv = tid >> 6, lane = tid & 63;
  const int ch = wv & 3;      // owned Y channel
  const int h  = wv >> 2;     // frame half
  const int fb = h * 256;     // frame base

  f2 yreg[NI]; float wreg[NI];

  // ---- stage X (zero-padded both ends)
  for (int c = 0; c < NC; ++c) {
    const size_t base = ((size_t)(b*NC + c)*NFQ + f)*NFR;
    for (int j = tid; j < XLEN; j += 512) {
      int n = j - XPAD;
      sXp[c][j] = (n >= 0 && n < NFR) ? mk2(Xr[base+n], Xi[base+n]) : mk2(0.f,0.f);
    }
  }
  // ---- stage Z (zero-padded tail); 512 threads cover NP exactly
  for (int k = 0; k < NBK; ++k) {
    const size_t zb = ((size_t)(b*NBK + k)*NFQ + f)*NFR;
    int n = tid;
    sZ[k][n] = (n < NFR) ? Zg[zb+n] : mk2(0.f,0.f);
  }
  // ---- Y + w into registers (own channel, own half)
  {
    const size_t yb = ((size_t)(b*NS + ch)*NFQ + f)*NFR;
    const int bs = b*NS + ch;
#pragma unroll
    for (int i = 0; i < NI; ++i) {
      int n = fb + lane + 64*i;
      if (n < NFR) {
        yreg[i] = Yg[yb+n];
        float a = 0.f;
#pragma unroll
        for (int cc = 0; cc < NCH; ++cc) a += wacc[((size_t)(cc*NB*NS + bs))*NFR + n];
        wreg[i] = 1.0f / fmaxf(a * (1.0f/(float)NFQ), EPSF);
      } else { yreg[i] = mk2(0.f,0.f); wreg[i] = 0.f; }
    }
  }
  if (tid < NS*NC) sW[tid/NC][tid%NC] = Wg[((size_t)(b*NS + tid/NC)*NFQ + f)*NC + tid%NC];
  else if (tid < NS*NC + NBK*NS) { int t=tid-NS*NC; sJ[t/NS][t%NS] = Jg[((size_t)(b*NBK+t/NS)*NFQ+f)*NS + t%NS]; }
  else if (tid < NS*NC + NBK*NS + NS*NS) { int t=tid-NS*NC-NBK*NS; sA[t/NS][t%NS] = Ag[((size_t)(b*NS+t/NS)*NFQ+f)*NS + t%NS]; }
  __syncthreads();

  f2 vloc[NC];   // bak-round v, in registers (every thread computes it)

  // ================= bak loop (4 barriers/round) =================
  for (int bak = 0; bak < NBK; ++bak) {
    // --- phase S: stage Zs; fold in previous round's A-update
    { int n = tid; sS[n] = sZ[bak][n] + sXp[NS+bak][XPAD+n]; }
    if (bak > 0 && tid < 16) {
      int s = tid >> 2, c = tid & 3;
      f2 v2[NS];
#pragma unroll
      for (int t = 0; t < NS; ++t)
        v2[t] = vloc[t] + cmul(sW[t][NS+0], vloc[NS+0]) + cmul(sW[t][NS+1], vloc[NS+1]);
      f2 den = mk2(1.f,0.f);
#pragma unroll
      for (int cc = 0; cc < NS; ++cc) den -= cmul(v2[cc], sgA[cc]);
      float m2 = cmag2(den) + EPSF;
      f2 mul = mk2(den.x/m2, -den.y/m2);
      sA[s][c] += cmul(sAv[s], cmul(sgA[c], mul));
    }
    __syncthreads();

    // --- phase R: partial reductions + g + sgo
    f2 zs[NI];
    {
      f2 pr2 = mk2(0.f,0.f), pi2 = mk2(0.f,0.f), dd2 = mk2(0.f,0.f);
#pragma unroll
      for (int i = 0; i < NI; ++i) {
        zs[i] = sS[fb + lane + 64*i];
        f2 wy = wreg[i]*yreg[i];
        pr2 += wy * zs[i];
        pi2 += wy.yx * mk2(zs[i].x, -zs[i].y);
        dd2 += (wreg[i]*zs[i]) * zs[i];
      }
      float pr = wred64(pr2.x+pr2.y), pi = wred64(pi2.x+pi2.y), dd = wred64(dd2.x+dd2.y);
      if (lane == 0) { sRed[0][wv][0]=pr; sRed[0][wv][1]=pi; sRed[0][wv][2]=dd; }
      if (ch < NBK) {   // waves 0,1,4,5: Z-channel partials (unweighted)
        f2 qr2 = mk2(0.f,0.f), qi2 = mk2(0.f,0.f), qd2 = mk2(0.f,0.f);
#pragma unroll
        for (int i = 0; i < NI; ++i) {
          f2 y = sZ[ch][fb + lane + 64*i];
          qr2 += y * zs[i];
          qi2 += y.yx * mk2(zs[i].x, -zs[i].y);
          qd2 += zs[i]*zs[i];
        }
        float qr = wred64(qr2.x+qr2.y), qi = wred64(qi2.x+qi2.y), qd = wred64(qd2.x+qd2.y);
        if (lane == 0) { sRed[0][wv][3]=qr; sRed[0][wv][4]=qi; sRed[0][wv][5]=qd; }
      }
    }
    if (tid < NC) {   // g[c] = conj( sum_s J[bak][s] * A2[s][c] )
      int c = tid; f2 acc = mk2(0.f,0.f);
      for (int s = 0; s < NS; ++s) {
        f2 a2;
        if (c < NS) a2 = sA[s][c];
        else {
          a2 = mk2(0.f,0.f);
          for (int k = 0; k < NS; ++k) a2 += cmul(sA[s][k], sW[k][c]);
        }
        acc += cmul(sJ[bak][s], a2);
      }
      sg[c] = conjc(acc);
    } else if (tid >= 8 && tid < 8+NS) {
      sgo[tid-8] = sJ[bak][tid-8];
    }
    __syncthreads();

    // --- phase U: per-thread combine + ell + v; Y/Z updates
    {
      f2 p[NC]; float d[NC];
#pragma unroll
      for (int c = 0; c < NS; ++c) {
        p[c] = mk2((sRed[0][c][0]+sRed[0][c+4][0])*(1.f/NFR),
                   (sRed[0][c][1]+sRed[0][c+4][1])*(1.f/NFR));
        d[c] = (sRed[0][c][2]+sRed[0][c+4][2])*(1.f/NFR);
      }
#pragma unroll
      for (int k = 0; k < NBK; ++k) {
        p[NS+k] = mk2((sRed[0][k][3]+sRed[0][k+4][3])*(1.f/NFR),
                      (sRed[0][k][4]+sRed[0][k+4][4])*(1.f/NFR));
        d[NS+k] = (sRed[0][k][5]+sRed[0][k+4][5])*(1.f/NFR);
      }
      float gdg = 0.f; f2 gdp = mk2(0.f,0.f);
#pragma unroll
      for (int c = 0; c < NC; ++c) {
        f2 gc = sg[c]; float id = 1.0f/(d[c] + EPSF);
        gdg += cmag2(gc) * id;
        gdp += id * cmulc(p[c], gc);
      }
      f2 bb = mk2(1.0f - gdp.x, -gdp.y);
      float b1 = cmag2(bb);
      float a = b1*gdg + TINYF;
      float beta = (-b1 + sqrtf(b1*b1 + 4.0f*a)) / (2.0f*a);
      f2 ell = (b1 > EPSF*EPSF) ? (beta*bb) : mk2(1.0f/sqrtf(EPSF + gdg), 0.f);
#pragma unroll
      for (int c = 0; c < NC; ++c)
        vloc[c] = (1.0f/(d[c] + EPSF)) * (p[c] - cmul(ell, sg[c]));
    }
    {
      f2 vc = vloc[ch];
#pragma unroll
      for (int i = 0; i < NI; ++i) yreg[i] -= cmul(vc, zs[i]);
      if (ch < NBK) {
        f2 v2c = vloc[NS+ch];
#pragma unroll
        for (int i = 0; i < NI; ++i) sZ[ch][fb + lane + 64*i] -= cmul(v2c, zs[i]);
      }
    }
    __syncthreads();

    // --- phase P1: Av, gA, W/J rank-1 updates (disjoint threads)
    if (tid < NS) {
      f2 v2[NS];
#pragma unroll
      for (int t = 0; t < NS; ++t)
        v2[t] = vloc[t] + cmul(sW[t][NS+0], vloc[NS+0]) + cmul(sW[t][NS+1], vloc[NS+1]);
      f2 acc = mk2(0.f,0.f);
#pragma unroll
      for (int c = 0; c < NS; ++c) acc += cmul(sA[tid][c], v2[c]);
      sAv[tid] = acc;
    } else if (tid < 2*NS) {
      int c = tid - NS; f2 acc = mk2(0.f,0.f);
#pragma unroll
      for (int s = 0; s < NS; ++s) acc += cmul(sgo[s], sA[s][c]);
      sgA[c] = acc;
    } else if (tid < 2*NS + 16) {
      int idx = tid - 2*NS; int cc = idx >> 2, d = idx & 3;
      sW[cc][d] -= cmul(vloc[cc], sgo[d]);
    } else if (tid < 2*NS + 16 + 8) {
      int idx = tid - 2*NS - 16; int k = idx >> 2, d = idx & 3;
      sJ[k][d] -= cmul(vloc[NS+k], sgo[d]);
    }
    __syncthreads();
  }

  // ================= type1 loop (2 barriers/round) =================
  for (int src = 0; src < NS; ++src) {
    // stage Ys (both halves) + final bak A-fold at src==0
    if (ch == src) {
#pragma unroll
      for (int i = 0; i < NI; ++i) sS[fb + lane + 64*i] = yreg[i];
    }
    if (src == 0 && tid < 16) {
      int s = tid >> 2, c = tid & 3;
      f2 v2[NS];
#pragma unroll
      for (int t = 0; t < NS; ++t)
        v2[t] = vloc[t] + cmul(sW[t][NS+0], vloc[NS+0]) + cmul(sW[t][NS+1], vloc[NS+1]);
      f2 den = mk2(1.f,0.f);
#pragma unroll
      for (int cc = 0; cc < NS; ++cc) den -= cmul(v2[cc], sgA[cc]);
      float m2 = cmag2(den) + EPSF;
      f2 mul = mk2(den.x/m2, -den.y/m2);
      sA[s][c] += cmul(sAv[s], cmul(sgA[c], mul));
    }
    __syncthreads();

    // partials + DPP + sRed; sWsrc copy; deferred mat_up1 (prev src)
    f2 ys[NI];
    {
      f2 nr2 = mk2(0.f,0.f), ni2 = mk2(0.f,0.f), dd2 = mk2(0.f,0.f);
#pragma unroll
      for (int i = 0; i < NI; ++i) {
        ys[i] = sS[fb + lane + 64*i];
        f2 wy = wreg[i]*yreg[i];
        nr2 += wy * ys[i];
        ni2 += wy.yx * mk2(ys[i].x, -ys[i].y);
        dd2 += (wreg[i]*ys[i]) * ys[i];
      }
      float nr = wred64(nr2.x+nr2.y), ni = wred64(ni2.x+ni2.y), dd = wred64(dd2.x+dd2.y);
      if (lane == 0) { sRed[0][wv][0]=nr; sRed[0][wv][1]=ni; sRed[0][wv][2]=dd; }
    }
    if (tid < NC) sWsrc[tid] = sW[src][tid];
    if (src > 0 && tid >= 8 && tid < 8+NS) {
      int r = tid - 8, prev = src - 1;
      f2 acc = mk2(0.f,0.f);
#pragma unroll
      for (int c = 0; c < NS; ++c) acc += cmul(sA[r][c], sv[c]);
      float den = 1.0f - sv[prev].x + EPSF;
      sA[r][prev] += (1.0f/den) * acc;
    }
    __syncthreads();

    // combine + v + update
    {
      float nrs = (sRed[0][ch][0]+sRed[0][ch+4][0])*(1.f/NFR);
      float nis = (sRed[0][ch][1]+sRed[0][ch+4][1])*(1.f/NFR);
      float dds = (sRed[0][ch][2]+sRed[0][ch+4][2])*(1.f/NFR);
      f2 vc;
      if (ch == src) vc = mk2(1.0f - 1.0f/sqrtf(fmaxf(dds, EPSF)), 0.f);
      else           vc = (1.0f/fmaxf(dds, EPSF)) * mk2(nrs, nis);
      if (h == 0 && lane == 0) sv[ch] = vc;
#pragma unroll
      for (int i = 0; i < NI; ++i) yreg[i] -= cmul(vc, ys[i]);
      if (h == 0 && lane < NC) sW[ch][lane] -= cmul(vc, sWsrc[lane]);
    }
  }
  // (mat_up1 for src=3 dead: A overwritten by Binv inverse)

  // ================= type2: pair-batched =================
  {
    f2 pr0=mk2(0,0), pi0=mk2(0,0), dd0=mk2(0,0);
    f2 pr1=mk2(0,0), pi1=mk2(0,0), dd1=mk2(0,0);
    f2 crr=mk2(0,0), cri=mk2(0,0);
    f2 z0c[NI], z1c[NI];
#pragma unroll
    for (int i = 0; i < NI; ++i) {
      f2 z0 = sZ[0][fb+lane+64*i], z1 = sZ[1][fb+lane+64*i];
      z0c[i] = z0; z1c[i] = z1;
      f2 wy = wreg[i]*yreg[i];
      f2 wz0 = wreg[i]*z0;
      pr0 += wy * z0;  pi0 += wy.yx * mk2(z0.x, -z0.y);  dd0 += wz0 * z0;
      pr1 += wy * z1;  pi1 += wy.yx * mk2(z1.x, -z1.y);  dd1 += (wreg[i]*z1) * z1;
      crr += wz0 * z1; cri += wz0.yx * mk2(z1.x, -z1.y);
    }
    float r0 = wred64(pr0.x+pr0.y), i0 = wred64(pi0.x+pi0.y), D0p = wred64(dd0.x+dd0.y);
    float r1 = wred64(pr1.x+pr1.y), i1 = wred64(pi1.x+pi1.y), D1p = wred64(dd1.x+dd1.y);
    float Rr = wred64(crr.x+crr.y), Ri = wred64(cri.x+cri.y);
    if (lane == 0) {
      sRed[1][wv][0]=r0; sRed[1][wv][1]=i0; sRed[1][wv][2]=D0p;
      sRed[1][wv][3]=r1; sRed[1][wv][4]=i1; sRed[1][wv][5]=D1p;
      sRed[1][wv][6]=Rr; sRed[1][wv][7]=Ri;
    }
    __syncthreads();
    float P0r = sRed[1][ch][0]+sRed[1][ch+4][0], P0i = sRed[1][ch][1]+sRed[1][ch+4][1];
    float D0  = sRed[1][ch][2]+sRed[1][ch+4][2];
    float P1r = sRed[1][ch][3]+sRed[1][ch+4][3], P1i = sRed[1][ch][4]+sRed[1][ch+4][4];
    float D1  = sRed[1][ch][5]+sRed[1][ch+4][5];
    float RR  = sRed[1][ch][6]+sRed[1][ch+4][6], RI = sRed[1][ch][7]+sRed[1][ch+4][7];
    f2 v0 = (1.0f/fmaxf(D0, EPSF)) * mk2(P0r, P0i);
    f2 P1c = mk2(P1r, P1i) - cmul(v0, mk2(RR, RI));
    f2 v1 = (1.0f/fmaxf(D1, EPSF)) * P1c;
#pragma unroll
    for (int i = 0; i < NI; ++i) yreg[i] -= cmul(v0, z0c[i]) + cmul(v1, z1c[i]);
    if (h == 0) {
      if (lane < NS) sW[ch][lane] -= cmul(v0, sJ[0][lane]) + cmul(v1, sJ[1][lane]);
      else if (lane == NS)   sW[ch][NS+0] += v0;
      else if (lane == NS+1) sW[ch][NS+1] += v1;
    }
  }
  __syncthreads();   // sW final before epilogue Binv; sRed banks free

  // ================= type3: 24 rounds, 1 barrier each (parity sRed) ========
  {
    int par = 0;
#pragma unroll 1
    for (int src = 0; src < NC; ++src) {
      const f2* __restrict__ xrow = &sXp[src][0];
#pragma unroll
      for (int tap = 0; tap < NT; ++tap) {
        const int xoff = XPAD - (NDLY + tap) + fb + lane;
        f2 xs[NI];
        f2 nr2 = mk2(0.f,0.f), ni2 = mk2(0.f,0.f), dd2 = mk2(0.f,0.f);
#pragma unroll
        for (int i = 0; i < NI; ++i) {
          xs[i] = xrow[xoff + 64*i];
          f2 wy = wreg[i]*yreg[i];
          nr2 += wy * xs[i];
          ni2 += wy.yx * mk2(xs[i].x, -xs[i].y);
          dd2 += (wreg[i]*xs[i]) * xs[i];
        }
        float nr = wred64(nr2.x+nr2.y), ni = wred64(ni2.x+ni2.y), dd = wred64(dd2.x+dd2.y);
        if (lane == 0) { sRed[par][wv][0]=nr; sRed[par][wv][1]=ni; sRed[par][wv][2]=dd; }
        __syncthreads();
        float nrs = sRed[par][ch][0]+sRed[par][ch+4][0];
        float nis = sRed[par][ch][1]+sRed[par][ch+4][1];
        float dds = sRed[par][ch][2]+sRed[par][ch+4][2];
        f2 vc = (1.0f/fmaxf(dds, EPSF)) * mk2(nrs, nis);
#pragma unroll
        for (int i = 0; i < NI; ++i) yreg[i] -= cmul(vc, xs[i]);
        par ^= 1;
      }
    }
  }

  // ================= epilogue =================
  {
    const size_t yb = ((size_t)(b*NS + ch)*NFQ + f)*NFR;
    if (last) {
#pragma unroll
      for (int i = 0; i < NI; ++i) { int n = fb+lane+64*i; if (n < NFR) outR[yb+n] = yreg[i].x; }
    } else {
#pragma unroll
      for (int i = 0; i < NI; ++i) { int n = fb+lane+64*i; if (n < NFR) Yg[yb+n] = yreg[i]; }
      // Binv stage (sW/sJ stable since type2 barrier)
      if (tid < 16) {
        int s = tid >> 2, d = tid & 3;
        f2 acc = sW[s][d];
        acc += cmul(sW[s][NS+0], sJ[0][d]);
        acc += cmul(sW[s][NS+1], sJ[1][d]);
        sB[s][d] = acc;
        sB[s][NS+d] = (s==d) ? mk2(1.f,0.f) : mk2(0.f,0.f);
      }
      __syncthreads();
      if (tid == 0) {   // Gauss-Jordan w/ partial pivoting
        for (int col = 0; col < NS; ++col) {
          int piv = col; float best = cmag2(sB[col][col]);
          for (int r = col+1; r < NS; ++r) { float m = cmag2(sB[r][col]); if (m > best) { best = m; piv = r; } }
          if (piv != col) for (int k = 0; k < 2*NS; ++k) { f2 t = sB[col][k]; sB[col][k] = sB[piv][k]; sB[piv][k] = t; }
          f2 ip = cinv(sB[col][col]);
          for (int k = 0; k < 2*NS; ++k) sB[col][k] = cmul(sB[col][k], ip);
          for (int r = 0; r < NS; ++r) if (r != col) {
            f2 fac = sB[r][col];
            for (int k = 0; k < 2*NS; ++k) sB[r][k] -= cmul(fac, sB[col][k]);
          }
        }
      }
      // overlap: Z/W/J write-back while tid0 runs GJ
      for (int k = 0; k < NBK; ++k) {
        const size_t zb = ((size_t)(b*NBK+k)*NFQ + f)*NFR;
        int n = tid;
        if (n < NFR) Zg[zb+n] = sZ[k][n];
      }
      if (tid >= 64 && tid < 64 + NS*NC) {
        int t = tid - 64;
        Wg[((size_t)(b*NS + t/NC)*NFQ + f)*NC + t%NC] = sW[t/NC][t%NC];
      } else if (tid >= 96 && tid < 96 + NBK*NS) {
        int t = tid - 96;
        Jg[((size_t)(b*NBK + t/NS)*NFQ + f)*NS + t%NS] = sJ[t/NS][t%NS];
      }
      __syncthreads();
      if (tid < NS*NS) Ag[((size_t)(b*NS + (tid>>2))*NFQ + f)*NS + (tid&3)] = sB[tid>>2][NS + (tid&3)];
    }
  }
}

// ---------------------------------------------------------------------------
extern "C" void kernel_launch(void* const* d_in, const int* in_sizes, int n_in,
                              void* d_out, int out_size, void* d_ws, size_t ws_size,
                              hipStream_t stream)
{
  (void)in_sizes; (void)n_in; (void)out_size; (void)ws_size;
  const float* Xr = (const float*)d_in[0];
  const float* Xi = (const float*)d_in[1];
  float* outR = (float*)d_out;   // d_out = re(Y), float32, (2,4,320,500)

  char* ws = (char*)d_ws;
  size_t off = 0;
  f2* Yg = (f2*)(ws + off); off += (size_t)NB*NS*NFQ*NFR*sizeof(f2);   // 10,240,000
  f2* Zg = (f2*)(ws + off); off += (size_t)NB*NBK*NFQ*NFR*sizeof(f2);  //  5,120,000
  f2* Wg = (f2*)(ws + off); off += (size_t)NB*NS*NFQ*NC*sizeof(f2);    //    122,880
  f2* Jg = (f2*)(ws + off); off += (size_t)NB*NBK*NFQ*NS*sizeof(f2);   //     40,960
  f2* Ag = (f2*)(ws + off); off += (size_t)NB*NS*NFQ*NS*sizeof(f2);    //     81,920
  float* wacc = (float*)(ws + off); off += (size_t)NCH*NB*NS*NFR*sizeof(float); // 128,000

  k_init<<<NB*NFQ, 256, 0, stream>>>(Xr, Xi, Yg, Zg, Wg, Jg, Ag);
  for (int it = 0; it < 2; ++it) {
    k_wpart<<<NB*NS*NCH, 512, 0, stream>>>(Yg, wacc);
    k_iter<<<NB*NFQ, 512, 0, stream>>>(Xr, Xi, Yg, Zg, Wg, Jg, Ag, wacc, outR, it == 1);
  }
}

// Round 8
// 119.113 us; speedup vs baseline: 1.3244x; 1.3244x over previous
//
#include <hip/hip_runtime.h>

#define NFR 500   // n_frames
#define NFQ 320   // n_freq
#define NB  2     // batch
#define NC  6     // n_chan
#define NS  4     // n_src
#define NBK 2     // n_chan - n_src
#define NT  4     // n_taps
#define NDLY 1    // n_delay
#define EPSF 1e-3f
#define TINYF 1e-20f

#define NP   512            // padded frame count (8 x 64 lanes)
#define XPAD 8              // leading zero-pad for shifted X reads
#define XLEN (XPAD + NP)
#define NCH  8              // f-chunks for w partial sums
#define FPC  (NFQ / NCH)    // 40 freqs per chunk

typedef float f2 __attribute__((ext_vector_type(2)));

__device__ __forceinline__ f2 mk2(float r, float i){ f2 t; t.x = r; t.y = i; return t; }
// complex ops on (re,im) pairs — select v_pk_* packed fp32
__device__ __forceinline__ f2 cmul(f2 a, f2 b){ return a.xx*b + a.yy*mk2(-b.y, b.x); }
__device__ __forceinline__ f2 cmulc(f2 a, f2 b){ return b.xx*a + b.yy*mk2(a.y, -a.x); } // a*conj(b)
__device__ __forceinline__ f2 conjc(f2 a){ return mk2(a.x, -a.y); }
__device__ __forceinline__ float cmag2(f2 a){ return a.x*a.x + a.y*a.y; }
__device__ __forceinline__ f2 cinv(f2 a){ float m = a.x*a.x + a.y*a.y; return mk2(a.x/m, -a.y/m); }

// wave64 sum-reduce via DPP (VALU latency); result uniform via readlane(63)
#define DPPF(x, ctrl) __int_as_float(__builtin_amdgcn_mov_dpp(__float_as_int(x), (ctrl), 0xF, 0xF, true))
__device__ __forceinline__ float wred64(float x){
  x += DPPF(x, 0x111);   // row_shr:1
  x += DPPF(x, 0x112);   // row_shr:2
  x += DPPF(x, 0x114);   // row_shr:4
  x += DPPF(x, 0x118);   // row_shr:8
  x += DPPF(x, 0x142);   // row_bcast:15
  x += DPPF(x, 0x143);   // row_bcast:31
  return __int_as_float(__builtin_amdgcn_readlane(__float_as_int(x), 63));
}

// ---------------------------------------------------------------------------
// w partials from X (iteration 0: Y == X[:4]):
// wacc[ch][bs][n] = sum_{f in chunk ch} (Xr^2 + Xi^2)[b, s, f, n]
// ---------------------------------------------------------------------------
__global__ __launch_bounds__(512) void k_wpartX(const float* __restrict__ Xr,
                                                const float* __restrict__ Xi,
                                                float* __restrict__ wacc)
{
  const int bs = blockIdx.x / NCH;       // b*NS + s
  const int ch = blockIdx.x % NCH;
  const int n  = threadIdx.x;
  if (n >= NFR) return;
  const int b = bs / NS, s = bs % NS;
  const size_t rowb = ((size_t)(b*NC + s)*NFQ)*NFR;
  float acc = 0.f;
  for (int ff = 0; ff < FPC; ++ff) {
    size_t idx = rowb + (size_t)(ch*FPC + ff)*NFR + n;
    float xr = Xr[idx], xi = Xi[idx];
    acc += xr*xr + xi*xi;
  }
  wacc[((size_t)(ch*NB*NS + bs))*NFR + n] = acc;
}

// ---------------------------------------------------------------------------
// w partials from Y (between iterations)
// ---------------------------------------------------------------------------
__global__ __launch_bounds__(512) void k_wpart(const f2* __restrict__ Yg,
                                               float* __restrict__ wacc)
{
  const int bs = blockIdx.x / NCH;
  const int ch = blockIdx.x % NCH;
  const int n  = threadIdx.x;
  if (n >= NFR) return;
  const f2* row = Yg + (size_t)bs*NFQ*NFR;
  f2 acc2 = mk2(0.f,0.f);
  for (int ff = 0; ff < FPC; ++ff) {
    f2 y = row[(size_t)(ch*FPC + ff)*NFR + n];
    acc2 += y*y;
  }
  wacc[((size_t)(ch*NB*NS + bs))*NFR + n] = acc2.x + acc2.y;
}

// ---------------------------------------------------------------------------
// one full iss_updates iteration per (b,f) block. Y,w in registers (wave-owned
// channel); X zero-padded in LDS; packed-fp32 math; DPP reductions; H dead.
// first=1: fold the init (C_XX -> J solve, W/A=eye, Z=JX - X[4:], Y=X[:4])
// into the prologue — no k_init kernel, no Y/Z/W/J/A global reads.
// ---------------------------------------------------------------------------
__global__ __launch_bounds__(256, 4) void k_iter(
  const float* __restrict__ Xr, const float* __restrict__ Xi,
  f2* __restrict__ Yg, f2* __restrict__ Zg,
  f2* __restrict__ Wg, f2* __restrict__ Jg, f2* __restrict__ Ag,
  const float* __restrict__ wacc, float* __restrict__ outR,
  const int first, const int last)
{
  __shared__ f2 sXp[NC][XLEN];   // front/back zero-padded X
  __shared__ f2 sZ[NBK][NP];
  __shared__ f2 sS[NP];
  __shared__ f2 sW[NS][NC];
  __shared__ f2 sJ[NBK][NS];
  __shared__ f2 sA[NS][NS];
  __shared__ f2 sB[NS][2*NS];    // GJ scratch; also C_XX staging when first
  __shared__ f2 sv[NC], sg[NC], sgo[NS];
  __shared__ float sd[NC];
  __shared__ f2 sp[NC];
  __shared__ f2 sAv[NS], sgA[NS], sWsrc[NC];

  const int bf = blockIdx.x;
  const int b = bf / NFQ, f = bf % NFQ;
  const int tid = threadIdx.x, wv = tid >> 6, lane = tid & 63;

  f2 yreg[8];   // wave-owned channel wv
  float wreg[8];

  // ---- stage X (zero-padded both ends)
  for (int c = 0; c < NC; ++c) {
    const size_t base = ((size_t)(b*NC + c)*NFQ + f)*NFR;
    for (int j = tid; j < XLEN; j += 256) {
      int n = j - XPAD;
      sXp[c][j] = (n >= 0 && n < NFR) ? mk2(Xr[base+n], Xi[base+n]) : mk2(0.f,0.f);
    }
  }

  if (first) {
    __syncthreads();   // X staged
    // ---- C_XX[s][d] partials into sB (s<4, d<6); W/A = eye
    for (int p = wv; p < NS*NC; p += 4) {
      int s = p / NC, d = p % NC;
      f2 ar2 = mk2(0.f,0.f), ai2 = mk2(0.f,0.f);
#pragma unroll
      for (int i = 0; i < 8; ++i) {
        int n = lane + 64*i;                     // padded zeros harmless
        f2 xs = sXp[s][XPAD+n], xd = sXp[d][XPAD+n];
        ar2 += xs * xd;
        ai2 += xs.yx * mk2(xd.x, -xd.y);
      }
      float ar = wred64(ar2.x + ar2.y), ai = wred64(ai2.x + ai2.y);
      if (lane == 0) sB[s][d] = mk2(ar*(1.f/NFR), ai*(1.f/NFR));
    }
    if (tid >= 192 && tid < 192 + NS*NC) {
      int t = tid - 192; sW[t/NC][t%NC] = (t/NC == t%NC) ? mk2(1.f,0.f) : mk2(0.f,0.f);
    } else if (tid >= 224 && tid < 224 + NS*NS) {
      int t = tid - 224; sA[t/NS][t%NS] = (t/NS == t%NS) ? mk2(1.f,0.f) : mk2(0.f,0.f);
    }
    __syncthreads();
    if (tid == 0) {   // diag-loaded GJ solve -> J
      f2 M[NS][NC];
      for (int s = 0; s < NS; ++s)
        for (int d = 0; d < NC; ++d) M[s][d] = sB[s][d];
      float dsum = 0.f;
      for (int s = 0; s < NS; ++s) dsum += sqrtf(cmag2(M[s][s]));
      float load = fmaxf(dsum*1e-5f, 1e-5f);
      for (int s = 0; s < NS; ++s) M[s][s].x += load;
      for (int col = 0; col < NS; ++col) {
        int piv = col; float best = cmag2(M[col][col]);
        for (int r = col+1; r < NS; ++r) { float m = cmag2(M[r][col]); if (m > best){best=m; piv=r;} }
        if (piv != col) for (int k = 0; k < NC; ++k) { f2 t=M[col][k]; M[col][k]=M[piv][k]; M[piv][k]=t; }
        f2 ip = cinv(M[col][col]);
        for (int k = col; k < NC; ++k) M[col][k] = cmul(M[col][k], ip);
        for (int r = 0; r < NS; ++r) if (r != col) {
          f2 fac = M[r][col];
          for (int k = col; k < NC; ++k) M[r][k] -= cmul(fac, M[col][k]);
        }
      }
      for (int k = 0; k < NBK; ++k)
        for (int s = 0; s < NS; ++s) sJ[k][s] = conjc(M[s][NS+k]);
    }
    __syncthreads();   // sJ ready
    // ---- Z = J X - X[4:], Y = X[:4] (regs), w from wacc
    for (int n = tid; n < NP; n += 256) {
      f2 x0 = sXp[0][XPAD+n], x1 = sXp[1][XPAD+n], x2 = sXp[2][XPAD+n], x3 = sXp[3][XPAD+n];
      f2 a0 = -sXp[NS+0][XPAD+n];
      a0 += cmul(sJ[0][0], x0); a0 += cmul(sJ[0][1], x1);
      a0 += cmul(sJ[0][2], x2); a0 += cmul(sJ[0][3], x3);
      f2 a1 = -sXp[NS+1][XPAD+n];
      a1 += cmul(sJ[1][0], x0); a1 += cmul(sJ[1][1], x1);
      a1 += cmul(sJ[1][2], x2); a1 += cmul(sJ[1][3], x3);
      sZ[0][n] = a0; sZ[1][n] = a1;
    }
    {
      const int bs = b*NS + wv;
#pragma unroll
      for (int i = 0; i < 8; ++i) {
        int n = lane + 64*i;
        yreg[i] = sXp[wv][XPAD+n];     // zero beyond NFR via pad
        if (n < NFR) {
          float a = 0.f;
#pragma unroll
          for (int cc = 0; cc < NCH; ++cc) a += wacc[((size_t)(cc*NB*NS + bs))*NFR + n];
          wreg[i] = 1.0f / fmaxf(a * (1.0f/(float)NFQ), EPSF);
        } else wreg[i] = 0.f;
      }
    }
    __syncthreads();   // sZ ready
  } else {
    // ---- stage Z (zero-padded tail)
    for (int k = 0; k < NBK; ++k) {
      const size_t zb = ((size_t)(b*NBK + k)*NFQ + f)*NFR;
      for (int n = tid; n < NP; n += 256) sZ[k][n] = (n < NFR) ? Zg[zb+n] : mk2(0.f,0.f);
    }
    // ---- Y + w into registers
    {
      const size_t yb = ((size_t)(b*NS + wv)*NFQ + f)*NFR;
      const int bs = b*NS + wv;
#pragma unroll
      for (int i = 0; i < 8; ++i) {
        int n = lane + 64*i;
        if (n < NFR) {
          yreg[i] = Yg[yb+n];
          float a = 0.f;
#pragma unroll
          for (int cc = 0; cc < NCH; ++cc) a += wacc[((size_t)(cc*NB*NS + bs))*NFR + n];
          wreg[i] = 1.0f / fmaxf(a * (1.0f/(float)NFQ), EPSF);
        } else { yreg[i] = mk2(0.f,0.f); wreg[i] = 0.f; }
      }
    }
    if (tid < NS*NC) sW[tid/NC][tid%NC] = Wg[((size_t)(b*NS + tid/NC)*NFQ + f)*NC + tid%NC];
    else if (tid < NS*NC + NBK*NS) { int t=tid-NS*NC; sJ[t/NS][t%NS] = Jg[((size_t)(b*NBK+t/NS)*NFQ+f)*NS + t%NS]; }
    else if (tid < NS*NC + NBK*NS + NS*NS) { int t=tid-NS*NC-NBK*NS; sA[t/NS][t%NS] = Ag[((size_t)(b*NS+t/NS)*NFQ+f)*NS + t%NS]; }
    __syncthreads();
  }

  f2 vloc[NC];   // bak-round v, persists in registers across barriers

  // ================= bak loop (4 barriers/round) =================
  for (int bak = 0; bak < NBK; ++bak) {
    // --- phase S: stage Zs; fold in previous round's A-update (P2)
    for (int n = tid; n < NP; n += 256)
      sS[n] = sZ[bak][n] + sXp[NS+bak][XPAD+n];
    if (bak > 0 && tid < 16) {
      int s = tid >> 2, c = tid & 3;
      f2 v2[NS];
#pragma unroll
      for (int t = 0; t < NS; ++t)
        v2[t] = vloc[t] + cmul(sW[t][NS+0], vloc[NS+0]) + cmul(sW[t][NS+1], vloc[NS+1]);
      f2 den = mk2(1.f,0.f);
#pragma unroll
      for (int cc = 0; cc < NS; ++cc) den -= cmul(v2[cc], sgA[cc]);
      float m2 = cmag2(den) + EPSF;
      f2 mul = mk2(den.x/m2, -den.y/m2);
      sA[s][c] += cmul(sAv[s], cmul(sgA[c], mul));
    }
    __syncthreads();

    // --- phase R: p,d reductions + g + sgo capture
    f2 zs[8];
    {
      f2 pr2 = mk2(0.f,0.f), pi2 = mk2(0.f,0.f), dd2 = mk2(0.f,0.f);
#pragma unroll
      for (int i = 0; i < 8; ++i) {
        zs[i] = sS[lane+64*i];
        f2 wy = wreg[i]*yreg[i];
        pr2 += wy * zs[i];
        pi2 += wy.yx * mk2(zs[i].x, -zs[i].y);
        dd2 += (wreg[i]*zs[i]) * zs[i];
      }
      float pr = wred64(pr2.x+pr2.y), pi = wred64(pi2.x+pi2.y), dd = wred64(dd2.x+dd2.y);
      if (lane == 0) { sp[wv] = mk2(pr*(1.f/NFR), pi*(1.f/NFR)); sd[wv] = dd*(1.f/NFR); }
      if (wv < NBK) {   // channels 4,5 (unweighted, rows = Z)
        f2 qr2 = mk2(0.f,0.f), qi2 = mk2(0.f,0.f), qd2 = mk2(0.f,0.f);
#pragma unroll
        for (int i = 0; i < 8; ++i) {
          f2 y = sZ[wv][lane+64*i];
          qr2 += y * zs[i];
          qi2 += y.yx * mk2(zs[i].x, -zs[i].y);
          qd2 += zs[i]*zs[i];
        }
        float qr = wred64(qr2.x+qr2.y), qi = wred64(qi2.x+qi2.y), qd = wred64(qd2.x+qd2.y);
        if (lane == 0) { sp[NS+wv] = mk2(qr*(1.f/NFR), qi*(1.f/NFR)); sd[NS+wv] = qd*(1.f/NFR); }
      }
    }
    if (tid < NC) {   // g[c] = conj( sum_s J[bak][s] * A2[s][c] )
      int c = tid; f2 acc = mk2(0.f,0.f);
      for (int s = 0; s < NS; ++s) {
        f2 a2;
        if (c < NS) a2 = sA[s][c];
        else {
          a2 = mk2(0.f,0.f);
          for (int k = 0; k < NS; ++k) a2 += cmul(sA[s][k], sW[k][c]);
        }
        acc += cmul(sJ[bak][s], a2);
      }
      sg[c] = conjc(acc);
    } else if (tid >= 8 && tid < 8+NS) {
      sgo[tid-8] = sJ[bak][tid-8];    // snapshot old J[bak]
    }
    __syncthreads();

    // --- phase U: every thread computes ell + v locally; Y/Z updates
    {
      float gdg = 0.f; f2 gdp = mk2(0.f,0.f);
#pragma unroll
      for (int c = 0; c < NC; ++c) {
        f2 gc = sg[c]; float id = 1.0f/(sd[c] + EPSF);
        gdg += cmag2(gc) * id;
        gdp += id * cmulc(sp[c], gc);
      }
      f2 bb = mk2(1.0f - gdp.x, -gdp.y);
      float b1 = cmag2(bb);
      float a = b1*gdg + TINYF;
      float beta = (-b1 + sqrtf(b1*b1 + 4.0f*a)) / (2.0f*a);
      f2 ell = (b1 > EPSF*EPSF) ? (beta*bb) : mk2(1.0f/sqrtf(EPSF + gdg), 0.f);
#pragma unroll
      for (int c = 0; c < NC; ++c)
        vloc[c] = (1.0f/(sd[c] + EPSF)) * (sp[c] - cmul(ell, sg[c]));
    }
    {
      f2 vc = vloc[wv];
#pragma unroll
      for (int i = 0; i < 8; ++i) yreg[i] -= cmul(vc, zs[i]);
      if (wv < NBK) {
        f2 v2c = vloc[NS+wv];
#pragma unroll
        for (int i = 0; i < 8; ++i) sZ[wv][lane+64*i] -= cmul(v2c, zs[i]);
      }
    }
    __syncthreads();

    // --- phase P1: Av, gA, W/J rank-1 updates (disjoint threads, v in regs)
    if (tid < NS) {
      f2 v2[NS];
#pragma unroll
      for (int t = 0; t < NS; ++t)
        v2[t] = vloc[t] + cmul(sW[t][NS+0], vloc[NS+0]) + cmul(sW[t][NS+1], vloc[NS+1]);
      f2 acc = mk2(0.f,0.f);
#pragma unroll
      for (int c = 0; c < NS; ++c) acc += cmul(sA[tid][c], v2[c]);
      sAv[tid] = acc;
    } else if (tid < 2*NS) {
      int c = tid - NS; f2 acc = mk2(0.f,0.f);
#pragma unroll
      for (int s = 0; s < NS; ++s) acc += cmul(sgo[s], sA[s][c]);
      sgA[c] = acc;
    } else if (tid < 2*NS + 16) {
      int idx = tid - 2*NS; int cc = idx >> 2, d = idx & 3;
      sW[cc][d] -= cmul(vloc[cc], sgo[d]);
    } else if (tid < 2*NS + 16 + 8) {
      int idx = tid - 2*NS - 16; int k = idx >> 2, d = idx & 3;
      sJ[k][d] -= cmul(vloc[NS+k], sgo[d]);
    }
    __syncthreads();
  }

  // ================= type1 loop (4 rounds) + deferred mat_up1 ==============
  for (int src = 0; src < NS; ++src) {
    if (wv == src) {
#pragma unroll
      for (int i = 0; i < 8; ++i) sS[lane+64*i] = yreg[i];
    }
    if (tid < NC) sWsrc[tid] = sW[src][tid];
    if (src == 0) {
      if (tid < 16) {     // final P2 of bak loop (uses vloc from bak=1)
        int s = tid >> 2, c = tid & 3;
        f2 v2[NS];
#pragma unroll
        for (int t = 0; t < NS; ++t)
          v2[t] = vloc[t] + cmul(sW[t][NS+0], vloc[NS+0]) + cmul(sW[t][NS+1], vloc[NS+1]);
        f2 den = mk2(1.f,0.f);
#pragma unroll
        for (int cc = 0; cc < NS; ++cc) den -= cmul(v2[cc], sgA[cc]);
        float m2 = cmag2(den) + EPSF;
        f2 mul = mk2(den.x/m2, -den.y/m2);
        sA[s][c] += cmul(sAv[s], cmul(sgA[c], mul));
      }
    } else if (tid >= 8 && tid < 8+NS) {   // mat_up1 for previous src
      int r = tid - 8, prev = src - 1;
      f2 acc = mk2(0.f,0.f);
#pragma unroll
      for (int c = 0; c < NS; ++c) acc += cmul(sA[r][c], sv[c]);
      float den = 1.0f - sv[prev].x + EPSF;
      sA[r][prev] += (1.0f/den) * acc;
    }
    __syncthreads();

    {
      f2 ys[8];
      f2 nr2 = mk2(0.f,0.f), ni2 = mk2(0.f,0.f), dd2 = mk2(0.f,0.f);
#pragma unroll
      for (int i = 0; i < 8; ++i) {
        ys[i] = sS[lane+64*i];
        f2 wy = wreg[i]*yreg[i];
        nr2 += wy * ys[i];
        ni2 += wy.yx * mk2(ys[i].x, -ys[i].y);
        dd2 += (wreg[i]*ys[i]) * ys[i];
      }
      float nr = wred64(nr2.x+nr2.y)*(1.f/NFR);
      float ni = wred64(ni2.x+ni2.y)*(1.f/NFR);
      float dd = wred64(dd2.x+dd2.y)*(1.f/NFR);
      f2 vc;
      if (wv == src) vc = mk2(1.0f - 1.0f/sqrtf(fmaxf(dd, EPSF)), 0.f);
      else           vc = (1.0f/fmaxf(dd, EPSF)) * mk2(nr, ni);
      if (lane == 0) sv[wv] = vc;
#pragma unroll
      for (int i = 0; i < 8; ++i) yreg[i] -= cmul(vc, ys[i]);
      if (lane < NC) sW[wv][lane] -= cmul(vc, sWsrc[lane]);
    }
    __syncthreads();
  }
  // (mat_up1 for src=3 is dead: A is overwritten by the Binv inverse below)

  // ================= type2: pair-batched (barrier-free, Z rows fixed) ======
  {
    f2 pr0=mk2(0,0), pi0=mk2(0,0), dd0=mk2(0,0);
    f2 pr1=mk2(0,0), pi1=mk2(0,0), dd1=mk2(0,0);
    f2 crr=mk2(0,0), cri=mk2(0,0);
    f2 z0c[8], z1c[8];
#pragma unroll
    for (int i = 0; i < 8; ++i) {
      f2 z0 = sZ[0][lane+64*i], z1 = sZ[1][lane+64*i];
      z0c[i] = z0; z1c[i] = z1;
      f2 wy = wreg[i]*yreg[i];
      f2 wz0 = wreg[i]*z0;
      pr0 += wy * z0;  pi0 += wy.yx * mk2(z0.x, -z0.y);  dd0 += wz0 * z0;
      pr1 += wy * z1;  pi1 += wy.yx * mk2(z1.x, -z1.y);  dd1 += (wreg[i]*z1) * z1;
      crr += wz0 * z1; cri += wz0.yx * mk2(z1.x, -z1.y);   // Rz = sum w z0 conj(z1)
    }
    float P0r = wred64(pr0.x+pr0.y), P0i = wred64(pi0.x+pi0.y), D0 = wred64(dd0.x+dd0.y);
    float P1r = wred64(pr1.x+pr1.y), P1i = wred64(pi1.x+pi1.y), D1 = wred64(dd1.x+dd1.y);
    float Rr  = wred64(crr.x+crr.y), Ri  = wred64(cri.x+cri.y);
    f2 v0 = (1.0f/fmaxf(D0, EPSF)) * mk2(P0r, P0i);
    f2 P1c = mk2(P1r, P1i) - cmul(v0, mk2(Rr, Ri));
    f2 v1 = (1.0f/fmaxf(D1, EPSF)) * P1c;
#pragma unroll
    for (int i = 0; i < 8; ++i) yreg[i] -= cmul(v0, z0c[i]) + cmul(v1, z1c[i]);
    if (lane < NS) sW[wv][lane] -= cmul(v0, sJ[0][lane]) + cmul(v1, sJ[1][lane]);
    else if (lane == NS)   sW[wv][NS+0] += v0;
    else if (lane == NS+1) sW[wv][NS+1] += v1;
  }
  __syncthreads();

  // ================= Binv -> inv (GJ on tid 0; overlaps type3) =============
  if (!last) {
    if (tid < 16) {
      int s = tid >> 2, d = tid & 3;
      f2 acc = sW[s][d];
      acc += cmul(sW[s][NS+0], sJ[0][d]);
      acc += cmul(sW[s][NS+1], sJ[1][d]);
      sB[s][d] = acc;
      sB[s][NS+d] = (s==d) ? mk2(1.f,0.f) : mk2(0.f,0.f);
    }
    __syncthreads();
    if (tid == 0) {
      for (int col = 0; col < NS; ++col) {
        int piv = col; float best = cmag2(sB[col][col]);
        for (int r = col+1; r < NS; ++r) { float m = cmag2(sB[r][col]); if (m > best) { best = m; piv = r; } }
        if (piv != col) for (int k = 0; k < 2*NS; ++k) { f2 t = sB[col][k]; sB[col][k] = sB[piv][k]; sB[piv][k] = t; }
        f2 ip = cinv(sB[col][col]);
        for (int k = 0; k < 2*NS; ++k) sB[col][k] = cmul(sB[col][k], ip);
        for (int r = 0; r < NS; ++r) if (r != col) {
          f2 fac = sB[r][col];
          for (int k = 0; k < 2*NS; ++k) sB[r][k] -= cmul(fac, sB[col][k]);
        }
      }
    }
  }

  // ================= type3: sequential rounds (barrier-free; regs Y/w) =====
  {
#pragma unroll 1
    for (int src = 0; src < NC; ++src) {
      const f2* __restrict__ xrow = &sXp[src][0];
#pragma unroll
      for (int tap = 0; tap < NT; ++tap) {
        const int xoff = XPAD - (NDLY + tap) + lane;
        f2 xs[8];
        f2 nr2 = mk2(0.f,0.f), ni2 = mk2(0.f,0.f), dd2 = mk2(0.f,0.f);
#pragma unroll
        for (int i = 0; i < 8; ++i) {
          xs[i] = xrow[xoff + 64*i];
          f2 wy = wreg[i]*yreg[i];
          nr2 += wy * xs[i];
          ni2 += wy.yx * mk2(xs[i].x, -xs[i].y);
          dd2 += (wreg[i]*xs[i]) * xs[i];
        }
        float nr = wred64(nr2.x+nr2.y), ni = wred64(ni2.x+ni2.y), dd = wred64(dd2.x+dd2.y);
        f2 vc = (1.0f/fmaxf(dd, EPSF)) * mk2(nr, ni);
#pragma unroll
        for (int i = 0; i < 8; ++i) yreg[i] -= cmul(vc, xs[i]);
      }
    }
  }

  // ================= epilogue =================
  {
    const size_t yb = ((size_t)(b*NS + wv)*NFQ + f)*NFR;
    if (last) {
#pragma unroll
      for (int i = 0; i < 8; ++i) { int n = lane+64*i; if (n < NFR) outR[yb+n] = yreg[i].x; }
    } else {
#pragma unroll
      for (int i = 0; i < 8; ++i) { int n = lane+64*i; if (n < NFR) Yg[yb+n] = yreg[i]; }
    }
  }
  if (!last) {
    __syncthreads();   // sB (GJ), sW/sJ cross-wave reads below
    for (int k = 0; k < NBK; ++k) {
      const size_t zb = ((size_t)(b*NBK+k)*NFQ + f)*NFR;
      for (int n = tid; n < NFR; n += 256) Zg[zb+n] = sZ[k][n];
    }
    if (tid < NS*NC) Wg[((size_t)(b*NS + tid/NC)*NFQ + f)*NC + tid%NC] = sW[tid/NC][tid%NC];
    else if (tid < NS*NC + NBK*NS) { int t = tid - NS*NC; Jg[((size_t)(b*NBK + t/NS)*NFQ + f)*NS + t%NS] = sJ[t/NS][t%NS]; }
    else if (tid < NS*NC + NBK*NS + NS*NS) { int t = tid - NS*NC - NBK*NS; Ag[((size_t)(b*NS + t/NS)*NFQ + f)*NS + t%NS] = sB[t/NS][NS + t%NS]; }
  }
}

// ---------------------------------------------------------------------------
extern "C" void kernel_launch(void* const* d_in, const int* in_sizes, int n_in,
                              void* d_out, int out_size, void* d_ws, size_t ws_size,
                              hipStream_t stream)
{
  (void)in_sizes; (void)n_in; (void)out_size; (void)ws_size;
  const float* Xr = (const float*)d_in[0];
  const float* Xi = (const float*)d_in[1];
  float* outR = (float*)d_out;   // d_out = re(Y), float32, (2,4,320,500)

  char* ws = (char*)d_ws;
  size_t off = 0;
  f2* Yg = (f2*)(ws + off); off += (size_t)NB*NS*NFQ*NFR*sizeof(f2);   // 10,240,000
  f2* Zg = (f2*)(ws + off); off += (size_t)NB*NBK*NFQ*NFR*sizeof(f2);  //  5,120,000
  f2* Wg = (f2*)(ws + off); off += (size_t)NB*NS*NFQ*NC*sizeof(f2);    //    122,880
  f2* Jg = (f2*)(ws + off); off += (size_t)NB*NBK*NFQ*NS*sizeof(f2);   //     40,960
  f2* Ag = (f2*)(ws + off); off += (size_t)NB*NS*NFQ*NS*sizeof(f2);    //     81,920
  float* wacc = (float*)(ws + off); off += (size_t)NCH*NB*NS*NFR*sizeof(float); // 128,000

  // iter 0 (init folded in): w from X, then fused init+iss
  k_wpartX<<<NB*NS*NCH, 512, 0, stream>>>(Xr, Xi, wacc);
  k_iter<<<NB*NFQ, 256, 0, stream>>>(Xr, Xi, Yg, Zg, Wg, Jg, Ag, wacc, outR, 1, 0);
  // iter 1 (last): w from Y, then iss, write re(Y) to out
  k_wpart<<<NB*NS*NCH, 512, 0, stream>>>(Yg, wacc);
  k_iter<<<NB*NFQ, 256, 0, stream>>>(Xr, Xi, Yg, Zg, Wg, Jg, Ag, wacc, outR, 0, 1);
}

// Round 9
// 114.438 us; speedup vs baseline: 1.3786x; 1.0409x over previous
//
#include <hip/hip_runtime.h>

#define NFR 500   // n_frames
#define NFQ 320   // n_freq
#define NB  2     // batch
#define NC  6     // n_chan
#define NS  4     // n_src
#define NBK 2     // n_chan - n_src
#define NT  4     // n_taps
#define NDLY 1    // n_delay
#define EPSF 1e-3f
#define TINYF 1e-20f

#define NP   512            // padded frame count (8 x 64 lanes)
#define XPAD 8              // leading zero-pad for shifted X reads
#define XLEN (XPAD + NP)
#define NCH  8              // f-chunks for w partial sums
#define FPC  (NFQ / NCH)    // 40 freqs per chunk

typedef float f2 __attribute__((ext_vector_type(2)));

__device__ __forceinline__ f2 mk2(float r, float i){ f2 t; t.x = r; t.y = i; return t; }
// complex ops on (re,im) pairs — select v_pk_* packed fp32
__device__ __forceinline__ f2 cmul(f2 a, f2 b){ return a.xx*b + a.yy*mk2(-b.y, b.x); }
__device__ __forceinline__ f2 cmulc(f2 a, f2 b){ return b.xx*a + b.yy*mk2(a.y, -a.x); } // a*conj(b)
__device__ __forceinline__ f2 conjc(f2 a){ return mk2(a.x, -a.y); }
__device__ __forceinline__ float cmag2(f2 a){ return a.x*a.x + a.y*a.y; }
__device__ __forceinline__ f2 cinv(f2 a){ float m = a.x*a.x + a.y*a.y; return mk2(a.x/m, -a.y/m); }

// wave64 sum-reduce via DPP (VALU latency); result uniform via readlane(63)
#define DPPF(x, ctrl) __int_as_float(__builtin_amdgcn_mov_dpp(__float_as_int(x), (ctrl), 0xF, 0xF, true))
__device__ __forceinline__ float wred64(float x){
  x += DPPF(x, 0x111);   // row_shr:1
  x += DPPF(x, 0x112);   // row_shr:2
  x += DPPF(x, 0x114);   // row_shr:4
  x += DPPF(x, 0x118);   // row_shr:8
  x += DPPF(x, 0x142);   // row_bcast:15
  x += DPPF(x, 0x143);   // row_bcast:31
  return __int_as_float(__builtin_amdgcn_readlane(__float_as_int(x), 63));
}

// ---------------------------------------------------------------------------
// w partials from X (iteration 0: Y == X[:4]):
// wacc[ch][bs][n] = sum_{f in chunk ch} (Xr^2 + Xi^2)[b, s, f, n]
// ---------------------------------------------------------------------------
__global__ __launch_bounds__(512) void k_wpartX(const float* __restrict__ Xr,
                                                const float* __restrict__ Xi,
                                                float* __restrict__ wacc)
{
  const int bs = blockIdx.x / NCH;       // b*NS + s
  const int ch = blockIdx.x % NCH;
  const int n  = threadIdx.x;
  if (n >= NFR) return;
  const int b = bs / NS, s = bs % NS;
  const size_t rowb = ((size_t)(b*NC + s)*NFQ)*NFR;
  float acc = 0.f;
  for (int ff = 0; ff < FPC; ++ff) {
    size_t idx = rowb + (size_t)(ch*FPC + ff)*NFR + n;
    float xr = Xr[idx], xi = Xi[idx];
    acc += xr*xr + xi*xi;
  }
  wacc[((size_t)(ch*NB*NS + bs))*NFR + n] = acc;
}

// ---------------------------------------------------------------------------
// w partials from Y (between iterations)
// ---------------------------------------------------------------------------
__global__ __launch_bounds__(512) void k_wpart(const f2* __restrict__ Yg,
                                               float* __restrict__ wacc)
{
  const int bs = blockIdx.x / NCH;
  const int ch = blockIdx.x % NCH;
  const int n  = threadIdx.x;
  if (n >= NFR) return;
  const f2* row = Yg + (size_t)bs*NFQ*NFR;
  f2 acc2 = mk2(0.f,0.f);
  for (int ff = 0; ff < FPC; ++ff) {
    f2 y = row[(size_t)(ch*FPC + ff)*NFR + n];
    acc2 += y*y;
  }
  wacc[((size_t)(ch*NB*NS + bs))*NFR + n] = acc2.x + acc2.y;
}

// ---------------------------------------------------------------------------
// one full iss_updates iteration per (b,f) block. Y,w in registers (wave-owned
// channel); X zero-padded in LDS; packed-fp32 math; DPP reductions; H dead.
// first=1: fold the init (C_XX -> J solve, W/A=eye, Z=JX - X[4:], Y=X[:4]).
// launch_bounds (256,3): grid limits occupancy to 2.5 blocks/CU anyway, so
// give the register allocator 128 VGPRs for ILP instead of capping at 64.
// ---------------------------------------------------------------------------
__global__ __launch_bounds__(256, 3) void k_iter(
  const float* __restrict__ Xr, const float* __restrict__ Xi,
  f2* __restrict__ Yg, f2* __restrict__ Zg,
  f2* __restrict__ Wg, f2* __restrict__ Jg, f2* __restrict__ Ag,
  const float* __restrict__ wacc, float* __restrict__ outR,
  const int first, const int last)
{
  __shared__ f2 sXp[NC][XLEN];   // front/back zero-padded X
  __shared__ f2 sZ[NBK][NP];
  __shared__ f2 sS[NP];
  __shared__ f2 sW[NS][NC];
  __shared__ f2 sJ[NBK][NS];
  __shared__ f2 sA[NS][NS];
  __shared__ f2 sB[NS][2*NS];    // GJ scratch; also C_XX staging when first
  __shared__ f2 sv[NC], sg[NC], sgo[NS];
  __shared__ float sd[NC];
  __shared__ f2 sp[NC];
  __shared__ f2 sAv[NS], sgA[NS], sWsrc[NC];

  const int bf = blockIdx.x;
  const int b = bf / NFQ, f = bf % NFQ;
  const int tid = threadIdx.x, wv = tid >> 6, lane = tid & 63;

  f2 yreg[8];   // wave-owned channel wv
  float wreg[8];

  // ---- stage X (zero-padded both ends)
  for (int c = 0; c < NC; ++c) {
    const size_t base = ((size_t)(b*NC + c)*NFQ + f)*NFR;
    for (int j = tid; j < XLEN; j += 256) {
      int n = j - XPAD;
      sXp[c][j] = (n >= 0 && n < NFR) ? mk2(Xr[base+n], Xi[base+n]) : mk2(0.f,0.f);
    }
  }

  if (first) {
    __syncthreads();   // X staged
    // ---- C_XX[s][d] partials into sB (s<4, d<6); W/A = eye
    for (int p = wv; p < NS*NC; p += 4) {
      int s = p / NC, d = p % NC;
      f2 ar2 = mk2(0.f,0.f), ai2 = mk2(0.f,0.f);
#pragma unroll
      for (int i = 0; i < 8; ++i) {
        int n = lane + 64*i;                     // padded zeros harmless
        f2 xs = sXp[s][XPAD+n], xd = sXp[d][XPAD+n];
        ar2 += xs * xd;
        ai2 += xs.yx * mk2(xd.x, -xd.y);
      }
      float ar = wred64(ar2.x + ar2.y), ai = wred64(ai2.x + ai2.y);
      if (lane == 0) sB[s][d] = mk2(ar*(1.f/NFR), ai*(1.f/NFR));
    }
    if (tid >= 192 && tid < 192 + NS*NC) {
      int t = tid - 192; sW[t/NC][t%NC] = (t/NC == t%NC) ? mk2(1.f,0.f) : mk2(0.f,0.f);
    } else if (tid >= 224 && tid < 224 + NS*NS) {
      int t = tid - 224; sA[t/NS][t%NS] = (t/NS == t%NS) ? mk2(1.f,0.f) : mk2(0.f,0.f);
    }
    __syncthreads();
    if (tid == 0) {   // diag-loaded GJ solve -> J
      f2 M[NS][NC];
      for (int s = 0; s < NS; ++s)
        for (int d = 0; d < NC; ++d) M[s][d] = sB[s][d];
      float dsum = 0.f;
      for (int s = 0; s < NS; ++s) dsum += sqrtf(cmag2(M[s][s]));
      float load = fmaxf(dsum*1e-5f, 1e-5f);
      for (int s = 0; s < NS; ++s) M[s][s].x += load;
      for (int col = 0; col < NS; ++col) {
        int piv = col; float best = cmag2(M[col][col]);
        for (int r = col+1; r < NS; ++r) { float m = cmag2(M[r][col]); if (m > best){best=m; piv=r;} }
        if (piv != col) for (int k = 0; k < NC; ++k) { f2 t=M[col][k]; M[col][k]=M[piv][k]; M[piv][k]=t; }
        f2 ip = cinv(M[col][col]);
        for (int k = col; k < NC; ++k) M[col][k] = cmul(M[col][k], ip);
        for (int r = 0; r < NS; ++r) if (r != col) {
          f2 fac = M[r][col];
          for (int k = col; k < NC; ++k) M[r][k] -= cmul(fac, M[col][k]);
        }
      }
      for (int k = 0; k < NBK; ++k)
        for (int s = 0; s < NS; ++s) sJ[k][s] = conjc(M[s][NS+k]);
    }
    __syncthreads();   // sJ ready
    // ---- Z = J X - X[4:], Y = X[:4] (regs), w from wacc
    for (int n = tid; n < NP; n += 256) {
      f2 x0 = sXp[0][XPAD+n], x1 = sXp[1][XPAD+n], x2 = sXp[2][XPAD+n], x3 = sXp[3][XPAD+n];
      f2 a0 = -sXp[NS+0][XPAD+n];
      a0 += cmul(sJ[0][0], x0); a0 += cmul(sJ[0][1], x1);
      a0 += cmul(sJ[0][2], x2); a0 += cmul(sJ[0][3], x3);
      f2 a1 = -sXp[NS+1][XPAD+n];
      a1 += cmul(sJ[1][0], x0); a1 += cmul(sJ[1][1], x1);
      a1 += cmul(sJ[1][2], x2); a1 += cmul(sJ[1][3], x3);
      sZ[0][n] = a0; sZ[1][n] = a1;
    }
    {
      const int bs = b*NS + wv;
#pragma unroll
      for (int i = 0; i < 8; ++i) {
        int n = lane + 64*i;
        yreg[i] = sXp[wv][XPAD+n];     // zero beyond NFR via pad
        if (n < NFR) {
          float a = 0.f;
#pragma unroll
          for (int cc = 0; cc < NCH; ++cc) a += wacc[((size_t)(cc*NB*NS + bs))*NFR + n];
          wreg[i] = 1.0f / fmaxf(a * (1.0f/(float)NFQ), EPSF);
        } else wreg[i] = 0.f;
      }
    }
    __syncthreads();   // sZ ready
  } else {
    // ---- stage Z (zero-padded tail)
    for (int k = 0; k < NBK; ++k) {
      const size_t zb = ((size_t)(b*NBK + k)*NFQ + f)*NFR;
      for (int n = tid; n < NP; n += 256) sZ[k][n] = (n < NFR) ? Zg[zb+n] : mk2(0.f,0.f);
    }
    // ---- Y + w into registers
    {
      const size_t yb = ((size_t)(b*NS + wv)*NFQ + f)*NFR;
      const int bs = b*NS + wv;
#pragma unroll
      for (int i = 0; i < 8; ++i) {
        int n = lane + 64*i;
        if (n < NFR) {
          yreg[i] = Yg[yb+n];
          float a = 0.f;
#pragma unroll
          for (int cc = 0; cc < NCH; ++cc) a += wacc[((size_t)(cc*NB*NS + bs))*NFR + n];
          wreg[i] = 1.0f / fmaxf(a * (1.0f/(float)NFQ), EPSF);
        } else { yreg[i] = mk2(0.f,0.f); wreg[i] = 0.f; }
      }
    }
    if (tid < NS*NC) sW[tid/NC][tid%NC] = Wg[((size_t)(b*NS + tid/NC)*NFQ + f)*NC + tid%NC];
    else if (tid < NS*NC + NBK*NS) { int t=tid-NS*NC; sJ[t/NS][t%NS] = Jg[((size_t)(b*NBK+t/NS)*NFQ+f)*NS + t%NS]; }
    else if (tid < NS*NC + NBK*NS + NS*NS) { int t=tid-NS*NC-NBK*NS; sA[t/NS][t%NS] = Ag[((size_t)(b*NS+t/NS)*NFQ+f)*NS + t%NS]; }
    __syncthreads();
  }

  f2 vloc[NC];   // bak-round v, persists in registers across barriers

  // ================= bak loop (4 barriers/round) =================
  for (int bak = 0; bak < NBK; ++bak) {
    // --- phase S: fold in previous round's A-update (P2); no Zs staging —
    //     each wave computes zs inline from sZ + sXp (identical values)
    if (bak > 0 && tid < 16) {
      int s = tid >> 2, c = tid & 3;
      f2 v2[NS];
#pragma unroll
      for (int t = 0; t < NS; ++t)
        v2[t] = vloc[t] + cmul(sW[t][NS+0], vloc[NS+0]) + cmul(sW[t][NS+1], vloc[NS+1]);
      f2 den = mk2(1.f,0.f);
#pragma unroll
      for (int cc = 0; cc < NS; ++cc) den -= cmul(v2[cc], sgA[cc]);
      float m2 = cmag2(den) + EPSF;
      f2 mul = mk2(den.x/m2, -den.y/m2);
      sA[s][c] += cmul(sAv[s], cmul(sgA[c], mul));
    }
    __syncthreads();

    // --- phase R: p,d reductions + g + sgo capture
    f2 zs[8];
    {
      f2 pr2 = mk2(0.f,0.f), pi2 = mk2(0.f,0.f), dd2 = mk2(0.f,0.f);
#pragma unroll
      for (int i = 0; i < 8; ++i) {
        int n = lane+64*i;
        zs[i] = sZ[bak][n] + sXp[NS+bak][XPAD+n];
        f2 wy = wreg[i]*yreg[i];
        pr2 += wy * zs[i];
        pi2 += wy.yx * mk2(zs[i].x, -zs[i].y);
        dd2 += (wreg[i]*zs[i]) * zs[i];
      }
      float pr = wred64(pr2.x+pr2.y), pi = wred64(pi2.x+pi2.y), dd = wred64(dd2.x+dd2.y);
      if (lane == 0) { sp[wv] = mk2(pr*(1.f/NFR), pi*(1.f/NFR)); sd[wv] = dd*(1.f/NFR); }
      if (wv < NBK) {   // channels 4,5 (unweighted, rows = Z)
        f2 qr2 = mk2(0.f,0.f), qi2 = mk2(0.f,0.f), qd2 = mk2(0.f,0.f);
#pragma unroll
        for (int i = 0; i < 8; ++i) {
          f2 y = sZ[wv][lane+64*i];
          qr2 += y * zs[i];
          qi2 += y.yx * mk2(zs[i].x, -zs[i].y);
          qd2 += zs[i]*zs[i];
        }
        float qr = wred64(qr2.x+qr2.y), qi = wred64(qi2.x+qi2.y), qd = wred64(qd2.x+qd2.y);
        if (lane == 0) { sp[NS+wv] = mk2(qr*(1.f/NFR), qi*(1.f/NFR)); sd[NS+wv] = qd*(1.f/NFR); }
      }
    }
    if (tid < NC) {   // g[c] = conj( sum_s J[bak][s] * A2[s][c] )
      int c = tid; f2 acc = mk2(0.f,0.f);
      for (int s = 0; s < NS; ++s) {
        f2 a2;
        if (c < NS) a2 = sA[s][c];
        else {
          a2 = mk2(0.f,0.f);
          for (int k = 0; k < NS; ++k) a2 += cmul(sA[s][k], sW[k][c]);
        }
        acc += cmul(sJ[bak][s], a2);
      }
      sg[c] = conjc(acc);
    } else if (tid >= 8 && tid < 8+NS) {
      sgo[tid-8] = sJ[bak][tid-8];    // snapshot old J[bak]
    }
    __syncthreads();

    // --- phase U: every thread computes ell + v locally; Y/Z updates
    {
      float gdg = 0.f; f2 gdp = mk2(0.f,0.f);
#pragma unroll
      for (int c = 0; c < NC; ++c) {
        f2 gc = sg[c]; float id = 1.0f/(sd[c] + EPSF);
        gdg += cmag2(gc) * id;
        gdp += id * cmulc(sp[c], gc);
      }
      f2 bb = mk2(1.0f - gdp.x, -gdp.y);
      float b1 = cmag2(bb);
      float a = b1*gdg + TINYF;
      float beta = (-b1 + sqrtf(b1*b1 + 4.0f*a)) / (2.0f*a);
      f2 ell = (b1 > EPSF*EPSF) ? (beta*bb) : mk2(1.0f/sqrtf(EPSF + gdg), 0.f);
#pragma unroll
      for (int c = 0; c < NC; ++c)
        vloc[c] = (1.0f/(sd[c] + EPSF)) * (sp[c] - cmul(ell, sg[c]));
    }
    {
      f2 vc = vloc[wv];
#pragma unroll
      for (int i = 0; i < 8; ++i) yreg[i] -= cmul(vc, zs[i]);
      if (wv < NBK) {
        f2 v2c = vloc[NS+wv];
#pragma unroll
        for (int i = 0; i < 8; ++i) sZ[wv][lane+64*i] -= cmul(v2c, zs[i]);
      }
    }
    __syncthreads();

    // --- phase P1: Av, gA, W/J rank-1 updates (disjoint threads, v in regs)
    if (tid < NS) {
      f2 v2[NS];
#pragma unroll
      for (int t = 0; t < NS; ++t)
        v2[t] = vloc[t] + cmul(sW[t][NS+0], vloc[NS+0]) + cmul(sW[t][NS+1], vloc[NS+1]);
      f2 acc = mk2(0.f,0.f);
#pragma unroll
      for (int c = 0; c < NS; ++c) acc += cmul(sA[tid][c], v2[c]);
      sAv[tid] = acc;
    } else if (tid < 2*NS) {
      int c = tid - NS; f2 acc = mk2(0.f,0.f);
#pragma unroll
      for (int s = 0; s < NS; ++s) acc += cmul(sgo[s], sA[s][c]);
      sgA[c] = acc;
    } else if (tid < 2*NS + 16) {
      int idx = tid - 2*NS; int cc = idx >> 2, d = idx & 3;
      sW[cc][d] -= cmul(vloc[cc], sgo[d]);
    } else if (tid < 2*NS + 16 + 8) {
      int idx = tid - 2*NS - 16; int k = idx >> 2, d = idx & 3;
      sJ[k][d] -= cmul(vloc[NS+k], sgo[d]);
    }
    __syncthreads();
  }

  // ================= type1 loop (4 rounds) + deferred mat_up1 ==============
  for (int src = 0; src < NS; ++src) {
    if (wv == src) {
#pragma unroll
      for (int i = 0; i < 8; ++i) sS[lane+64*i] = yreg[i];
    }
    if (tid < NC) sWsrc[tid] = sW[src][tid];
    if (src == 0) {
      if (tid < 16) {     // final P2 of bak loop (uses vloc from bak=1)
        int s = tid >> 2, c = tid & 3;
        f2 v2[NS];
#pragma unroll
        for (int t = 0; t < NS; ++t)
          v2[t] = vloc[t] + cmul(sW[t][NS+0], vloc[NS+0]) + cmul(sW[t][NS+1], vloc[NS+1]);
        f2 den = mk2(1.f,0.f);
#pragma unroll
        for (int cc = 0; cc < NS; ++cc) den -= cmul(v2[cc], sgA[cc]);
        float m2 = cmag2(den) + EPSF;
        f2 mul = mk2(den.x/m2, -den.y/m2);
        sA[s][c] += cmul(sAv[s], cmul(sgA[c], mul));
      }
    } else if (tid >= 8 && tid < 8+NS) {   // mat_up1 for previous src
      int r = tid - 8, prev = src - 1;
      f2 acc = mk2(0.f,0.f);
#pragma unroll
      for (int c = 0; c < NS; ++c) acc += cmul(sA[r][c], sv[c]);
      float den = 1.0f - sv[prev].x + EPSF;
      sA[r][prev] += (1.0f/den) * acc;
    }
    __syncthreads();

    {
      f2 ys[8];
      f2 nr2 = mk2(0.f,0.f), ni2 = mk2(0.f,0.f), dd2 = mk2(0.f,0.f);
#pragma unroll
      for (int i = 0; i < 8; ++i) {
        ys[i] = sS[lane+64*i];
        f2 wy = wreg[i]*yreg[i];
        nr2 += wy * ys[i];
        ni2 += wy.yx * mk2(ys[i].x, -ys[i].y);
        dd2 += (wreg[i]*ys[i]) * ys[i];
      }
      float nr = wred64(nr2.x+nr2.y)*(1.f/NFR);
      float ni = wred64(ni2.x+ni2.y)*(1.f/NFR);
      float dd = wred64(dd2.x+dd2.y)*(1.f/NFR);
      f2 vc;
      if (wv == src) vc = mk2(1.0f - 1.0f/sqrtf(fmaxf(dd, EPSF)), 0.f);
      else           vc = (1.0f/fmaxf(dd, EPSF)) * mk2(nr, ni);
      if (lane == 0) sv[wv] = vc;
#pragma unroll
      for (int i = 0; i < 8; ++i) yreg[i] -= cmul(vc, ys[i]);
      if (lane < NC) sW[wv][lane] -= cmul(vc, sWsrc[lane]);
    }
    __syncthreads();
  }
  // (mat_up1 for src=3 is dead: A is overwritten by the Binv inverse below)

  // ================= type2: pair-batched (barrier-free, Z rows fixed) ======
  {
    f2 pr0=mk2(0,0), pi0=mk2(0,0), dd0=mk2(0,0);
    f2 pr1=mk2(0,0), pi1=mk2(0,0), dd1=mk2(0,0);
    f2 crr=mk2(0,0), cri=mk2(0,0);
    f2 z0c[8], z1c[8];
#pragma unroll
    for (int i = 0; i < 8; ++i) {
      f2 z0 = sZ[0][lane+64*i], z1 = sZ[1][lane+64*i];
      z0c[i] = z0; z1c[i] = z1;
      f2 wy = wreg[i]*yreg[i];
      f2 wz0 = wreg[i]*z0;
      pr0 += wy * z0;  pi0 += wy.yx * mk2(z0.x, -z0.y);  dd0 += wz0 * z0;
      pr1 += wy * z1;  pi1 += wy.yx * mk2(z1.x, -z1.y);  dd1 += (wreg[i]*z1) * z1;
      crr += wz0 * z1; cri += wz0.yx * mk2(z1.x, -z1.y);   // Rz = sum w z0 conj(z1)
    }
    float P0r = wred64(pr0.x+pr0.y), P0i = wred64(pi0.x+pi0.y), D0 = wred64(dd0.x+dd0.y);
    float P1r = wred64(pr1.x+pr1.y), P1i = wred64(pi1.x+pi1.y), D1 = wred64(dd1.x+dd1.y);
    float Rr  = wred64(crr.x+crr.y), Ri  = wred64(cri.x+cri.y);
    f2 v0 = (1.0f/fmaxf(D0, EPSF)) * mk2(P0r, P0i);
    f2 P1c = mk2(P1r, P1i) - cmul(v0, mk2(Rr, Ri));
    f2 v1 = (1.0f/fmaxf(D1, EPSF)) * P1c;
#pragma unroll
    for (int i = 0; i < 8; ++i) yreg[i] -= cmul(v0, z0c[i]) + cmul(v1, z1c[i]);
    if (lane < NS) sW[wv][lane] -= cmul(v0, sJ[0][lane]) + cmul(v1, sJ[1][lane]);
    else if (lane == NS)   sW[wv][NS+0] += v0;
    else if (lane == NS+1) sW[wv][NS+1] += v1;
  }
  __syncthreads();

  // ================= Binv -> inv (GJ on tid 0; overlaps type3) =============
  if (!last) {
    if (tid < 16) {
      int s = tid >> 2, d = tid & 3;
      f2 acc = sW[s][d];
      acc += cmul(sW[s][NS+0], sJ[0][d]);
      acc += cmul(sW[s][NS+1], sJ[1][d]);
      sB[s][d] = acc;
      sB[s][NS+d] = (s==d) ? mk2(1.f,0.f) : mk2(0.f,0.f);
    }
    __syncthreads();
    if (tid == 0) {
      for (int col = 0; col < NS; ++col) {
        int piv = col; float best = cmag2(sB[col][col]);
        for (int r = col+1; r < NS; ++r) { float m = cmag2(sB[r][col]); if (m > best) { best = m; piv = r; } }
        if (piv != col) for (int k = 0; k < 2*NS; ++k) { f2 t = sB[col][k]; sB[col][k] = sB[piv][k]; sB[piv][k] = t; }
        f2 ip = cinv(sB[col][col]);
        for (int k = 0; k < 2*NS; ++k) sB[col][k] = cmul(sB[col][k], ip);
        for (int r = 0; r < NS; ++r) if (r != col) {
          f2 fac = sB[r][col];
          for (int k = 0; k < 2*NS; ++k) sB[r][k] -= cmul(fac, sB[col][k]);
        }
      }
    }
  }

  // ================= type3: sequential rounds (barrier-free; regs Y/w) =====
  {
#pragma unroll 1
    for (int src = 0; src < NC; ++src) {
      const f2* __restrict__ xrow = &sXp[src][0];
#pragma unroll
      for (int tap = 0; tap < NT; ++tap) {
        const int xoff = XPAD - (NDLY + tap) + lane;
        f2 xs[8];
        f2 nr2 = mk2(0.f,0.f), ni2 = mk2(0.f,0.f), dd2 = mk2(0.f,0.f);
#pragma unroll
        for (int i = 0; i < 8; ++i) {
          xs[i] = xrow[xoff + 64*i];
          f2 wy = wreg[i]*yreg[i];
          nr2 += wy * xs[i];
          ni2 += wy.yx * mk2(xs[i].x, -xs[i].y);
          dd2 += (wreg[i]*xs[i]) * xs[i];
        }
        float nr = wred64(nr2.x+nr2.y), ni = wred64(ni2.x+ni2.y), dd = wred64(dd2.x+dd2.y);
        f2 vc = (1.0f/fmaxf(dd, EPSF)) * mk2(nr, ni);
#pragma unroll
        for (int i = 0; i < 8; ++i) yreg[i] -= cmul(vc, xs[i]);
      }
    }
  }

  // ================= epilogue =================
  {
    const size_t yb = ((size_t)(b*NS + wv)*NFQ + f)*NFR;
    if (last) {
#pragma unroll
      for (int i = 0; i < 8; ++i) { int n = lane+64*i; if (n < NFR) outR[yb+n] = yreg[i].x; }
    } else {
#pragma unroll
      for (int i = 0; i < 8; ++i) { int n = lane+64*i; if (n < NFR) Yg[yb+n] = yreg[i]; }
    }
  }
  if (!last) {
    __syncthreads();   // sB (GJ), sW/sJ cross-wave reads below
    for (int k = 0; k < NBK; ++k) {
      const size_t zb = ((size_t)(b*NBK+k)*NFQ + f)*NFR;
      for (int n = tid; n < NFR; n += 256) Zg[zb+n] = sZ[k][n];
    }
    if (tid < NS*NC) Wg[((size_t)(b*NS + tid/NC)*NFQ + f)*NC + tid%NC] = sW[tid/NC][tid%NC];
    else if (tid < NS*NC + NBK*NS) { int t = tid - NS*NC; Jg[((size_t)(b*NBK + t/NS)*NFQ + f)*NS + t%NS] = sJ[t/NS][t%NS]; }
    else if (tid < NS*NC + NBK*NS + NS*NS) { int t = tid - NS*NC - NBK*NS; Ag[((size_t)(b*NS + t/NS)*NFQ + f)*NS + t%NS] = sB[t/NS][NS + t%NS]; }
  }
}

// ---------------------------------------------------------------------------
extern "C" void kernel_launch(void* const* d_in, const int* in_sizes, int n_in,
                              void* d_out, int out_size, void* d_ws, size_t ws_size,
                              hipStream_t stream)
{
  (void)in_sizes; (void)n_in; (void)out_size; (void)ws_size;
  const float* Xr = (const float*)d_in[0];
  const float* Xi = (const float*)d_in[1];
  float* outR = (float*)d_out;   // d_out = re(Y), float32, (2,4,320,500)

  char* ws = (char*)d_ws;
  size_t off = 0;
  f2* Yg = (f2*)(ws + off); off += (size_t)NB*NS*NFQ*NFR*sizeof(f2);   // 10,240,000
  f2* Zg = (f2*)(ws + off); off += (size_t)NB*NBK*NFQ*NFR*sizeof(f2);  //  5,120,000
  f2* Wg = (f2*)(ws + off); off += (size_t)NB*NS*NFQ*NC*sizeof(f2);    //    122,880
  f2* Jg = (f2*)(ws + off); off += (size_t)NB*NBK*NFQ*NS*sizeof(f2);   //     40,960
  f2* Ag = (f2*)(ws + off); off += (size_t)NB*NS*NFQ*NS*sizeof(f2);    //     81,920
  float* wacc = (float*)(ws + off); off += (size_t)NCH*NB*NS*NFR*sizeof(float); // 128,000

  // iter 0 (init folded in): w from X, then fused init+iss
  k_wpartX<<<NB*NS*NCH, 512, 0, stream>>>(Xr, Xi, wacc);
  k_iter<<<NB*NFQ, 256, 0, stream>>>(Xr, Xi, Yg, Zg, Wg, Jg, Ag, wacc, outR, 1, 0);
  // iter 1 (last): w from Y, then iss, write re(Y) to out
  k_wpart<<<NB*NS*NCH, 512, 0, stream>>>(Yg, wacc);
  k_iter<<<NB*NFQ, 256, 0, stream>>>(Xr, Xi, Yg, Zg, Wg, Jg, Ag, wacc, outR, 0, 1);
}